// Round 7
// baseline (644.351 us; speedup 1.0000x reference)
//
#include <hip/hip_runtime.h>
#include <hip/hip_bf16.h>

// Problem constants
#define B_   64
#define N_   512
#define D_   256
#define H_   4
#define HD_  64

typedef __hip_bfloat16 bf16;
typedef __attribute__((ext_vector_type(8))) short short8;
typedef __attribute__((ext_vector_type(4))) float floatx4;

__device__ __forceinline__ float bf2f(bf16 v) { return __bfloat162float(v); }
__device__ __forceinline__ unsigned short f2us(float f) {
    bf16 h = __float2bfloat16(f);
    union { bf16 h; unsigned short u; } c; c.h = h; return c.u;
}

// ---------------------------------------------------------------------------
// Weight pre-convert: fp32 -> bf16, zero-padded rows Kreal -> Kp (K%32==0).
// dst layout: Wr[256*800] Wf[256*704] Wq Wk Wv Wo W1 W2 [256*256 each].
// ---------------------------------------------------------------------------
__global__ __launch_bounds__(256)
void convw_k(const float* __restrict__ Wr, const float* __restrict__ Wf,
             const float* __restrict__ Wq, const float* __restrict__ Wk,
             const float* __restrict__ Wv, const float* __restrict__ Wo,
             const float* __restrict__ W1, const float* __restrict__ W2,
             bf16* __restrict__ dst)
{
    const int seg = blockIdx.y;
    const float* src; int Kreal, Kp; size_t off;
    switch (seg) {
        case 0: src = Wr; Kreal = 769; Kp = 800; off = 0; break;
        case 1: src = Wf; Kreal = 674; Kp = 704; off = 256 * 800; break;
        default:
            src = (seg == 2) ? Wq : (seg == 3) ? Wk : (seg == 4) ? Wv
                : (seg == 5) ? Wo : (seg == 6) ? W1 : W2;
            Kreal = 256; Kp = 256;
            off = 256 * 800 + 256 * 704 + (size_t)(seg - 2) * 256 * 256;
            break;
    }
    const int idx = blockIdx.x * 256 + threadIdx.x;   // unit = 8 outputs
    if (idx >= 256 * Kp / 8) return;
    const int rowk = idx * 8;
    const int n = rowk / Kp, k0 = rowk % Kp;
    unsigned short tmp[8];
    #pragma unroll
    for (int j = 0; j < 8; ++j) {
        int kk = k0 + j;
        tmp[j] = f2us(kk < Kreal ? src[(size_t)n * Kreal + kk] : 0.f);
    }
    *(short8*)&dst[off + (size_t)rowk] = *(short8*)tmp;
}

// ---------------------------------------------------------------------------
// Positional-embedding table: pe[n][c], n<512, c<256. grid 512 x 256 thr.
// ---------------------------------------------------------------------------
__global__ __launch_bounds__(256)
void pe_k(float* __restrict__ pe)
{
    const int n = blockIdx.x, c = threadIdx.x;
    const int j = c & ~1;
    float freq = __expf(-(float)j * (9.210340371976184f / 256.0f)); // ln(10000)/d
    float ang = (float)n * freq;
    pe[n * 256 + c] = (c & 1) ? cosf(ang) : sinf(ang);
}

// ---------------------------------------------------------------------------
// Barrier-free direct-fragment MFMA GEMM. 64x256 tile, 512 threads (8 waves):
// wave = (row-half rh = w&1: 32 rows, col-quarter cq = w>>2..: 64 cols).
// Every MFMA fragment is loaded straight from global memory per-lane:
//   A-frag: row m0+rh*32+im*16+fr, k = t*32 + quad*8 (+j)   [bf16: 16B load]
//   B-frag: row cq*64+in*16+fr of bf16 weights (L2-hot), same k
// No LDS staging, no __syncthreads in the K-loop -- the compiler pipelines
// the pure load->cvt->mfma dataflow; 16 waves/CU provide TLP.
// F32A: A read as raw fp32 (row stride Kreal, unaligned rows -> scalar
// loads) and converted in-register; guard only on the (uniform) last tile.
// Epilogue fuses bias/PE/ReLU/residual/LayerNorm/mean-pool-partials or V^T.
// ---------------------------------------------------------------------------
template<bool F32A>
__global__ __launch_bounds__(512, 4)
void gemm_df(const bf16* __restrict__ A, const float* __restrict__ A32,
             int lda, int Kreal,
             const bf16* __restrict__ W, int ldw,
             const float* __restrict__ bias, const bf16* __restrict__ res,
             const float* __restrict__ pe,
             const float* __restrict__ g, const float* __restrict__ bln,
             bf16* __restrict__ C, float* __restrict__ pp,
             int Kp, int relu, int tv)
{
    __shared__ float s_mu[64][4], s_sq[64][4];   // 2 KB (LN cross-wave reduce)

    const int tid = threadIdx.x;
    const int m0 = blockIdx.x * 64;
    const int lane = tid & 63, w = tid >> 6;
    const int rh = w & 1;            // row half: rows rh*32 .. +32
    const int cq = w >> 1;           // col quarter: cols cq*64 .. +64
    const int fr = lane & 15, quad = lane >> 4;
    const int nt = Kp / 32;

    const unsigned short* wp = (const unsigned short*)W
        + (size_t)(cq * 64 + fr) * ldw + quad * 8;
    const float* ap32 = F32A
        ? A32 + (size_t)(m0 + rh * 32 + fr) * Kreal + quad * 8 : nullptr;
    const unsigned short* apb = F32A ? nullptr
        : (const unsigned short*)A + (size_t)(m0 + rh * 32 + fr) * lda + quad * 8;

    floatx4 acc[2][4] = {};

    auto ldB = [&](int t, short8 (&fb)[4]) {
        const int k0 = t * 32;
        #pragma unroll
        for (int in = 0; in < 4; ++in)
            fb[in] = *(const short8*)(wp + (size_t)(in * 16) * ldw + k0);
    };
    auto step = [&](short8 (&a)[2], short8 (&b)[4]) {
        #pragma unroll
        for (int in = 0; in < 4; ++in)
            #pragma unroll
            for (int im = 0; im < 2; ++im)
                acc[im][in] = __builtin_amdgcn_mfma_f32_16x16x32_bf16(
                    a[im], b[in], acc[im][in], 0, 0, 0);
    };

    if constexpr (F32A) {
        auto ldA = [&](int t, float (&fa)[2][8]) {
            const int k0 = t * 32;
            if (k0 + 32 <= Kreal) {
                #pragma unroll
                for (int im = 0; im < 2; ++im)
                    #pragma unroll
                    for (int j = 0; j < 8; ++j)
                        fa[im][j] = ap32[(size_t)(im * 16) * Kreal + k0 + j];
            } else {
                #pragma unroll
                for (int im = 0; im < 2; ++im)
                    #pragma unroll
                    for (int j = 0; j < 8; ++j) {
                        const int kk = k0 + quad * 8 + j;
                        fa[im][j] = (kk < Kreal)
                            ? ap32[(size_t)(im * 16) * Kreal + k0 + j] : 0.f;
                    }
            }
        };
        auto cvt2 = [&](float (&fa)[2][8], short8 (&pa)[2]) {
            #pragma unroll
            for (int im = 0; im < 2; ++im) {
                unsigned short uw[8];
                #pragma unroll
                for (int j = 0; j < 8; ++j) uw[j] = f2us(fa[im][j]);
                pa[im] = *(short8*)uw;
            }
        };

        float faA[2][8], faB[2][8];
        short8 fbA[4], fbB[4];
        ldA(0, faA); ldB(0, fbA);
        for (int t = 0; t < nt; t += 2) {
            if (t + 1 < nt) { ldA(t + 1, faB); ldB(t + 1, fbB); }
            short8 pa[2]; cvt2(faA, pa);
            step(pa, fbA);
            if (t + 1 < nt) {
                if (t + 2 < nt) { ldA(t + 2, faA); ldB(t + 2, fbA); }
                short8 pb[2]; cvt2(faB, pb);
                step(pb, fbB);
            }
        }
    } else {
        auto ldAb = [&](int t, short8 (&fa)[2]) {
            const int k0 = t * 32;
            #pragma unroll
            for (int im = 0; im < 2; ++im)
                fa[im] = *(const short8*)(apb + (size_t)(im * 16) * lda + k0);
        };
        short8 faA[2], faB[2], fbA[4], fbB[4];
        ldAb(0, faA); ldB(0, fbA);
        for (int t = 0; t < nt; t += 2) {
            if (t + 1 < nt) { ldAb(t + 1, faB); ldB(t + 1, fbB); }
            step(faA, fbA);
            if (t + 1 < nt) {
                if (t + 2 < nt) { ldAb(t + 2, faA); ldB(t + 2, fbA); }
                step(faB, fbB);
            }
        }
    }

    // ---- epilogue: bias (+pe) (+relu) (+res), all in fp32 regs ----
    // C/D layout: col = fr, row = quad*4 + reg (within each 16x16 frag)
    #pragma unroll
    for (int in = 0; in < 4; ++in) {
        const int n = cq * 64 + in * 16 + fr;
        const float bi = bias[n];
        #pragma unroll
        for (int im = 0; im < 2; ++im) {
            #pragma unroll
            for (int reg = 0; reg < 4; ++reg) {
                const int m = m0 + rh * 32 + im * 16 + quad * 4 + reg;
                float v = acc[im][in][reg] + bi;
                if (pe)   v += pe[((m & (N_ - 1)) << 8) + n];
                if (relu) v = fmaxf(v, 0.f);
                if (res)  v += bf2f(res[((size_t)m << 8) + n]);
                acc[im][in][reg] = v;
            }
        }
    }

    if (g) {
        // fused LayerNorm over the full row (256 cols across 4 col-waves)
        #pragma unroll
        for (int im = 0; im < 2; ++im) {
            #pragma unroll
            for (int reg = 0; reg < 4; ++reg) {
                float ps = acc[im][0][reg] + acc[im][1][reg]
                         + acc[im][2][reg] + acc[im][3][reg];
                float pq = acc[im][0][reg] * acc[im][0][reg]
                         + acc[im][1][reg] * acc[im][1][reg]
                         + acc[im][2][reg] * acc[im][2][reg]
                         + acc[im][3][reg] * acc[im][3][reg];
                #pragma unroll
                for (int off = 1; off < 16; off <<= 1) {
                    ps += __shfl_xor(ps, off, 64);
                    pq += __shfl_xor(pq, off, 64);
                }
                if (fr == 0) {
                    const int r = rh * 32 + im * 16 + quad * 4 + reg;
                    s_mu[r][cq] = ps;
                    s_sq[r][cq] = pq;
                }
            }
        }
        __syncthreads();
        #pragma unroll
        for (int im = 0; im < 2; ++im) {
            #pragma unroll
            for (int reg = 0; reg < 4; ++reg) {
                const int r = rh * 32 + im * 16 + quad * 4 + reg;
                const float mu = (s_mu[r][0] + s_mu[r][1] + s_mu[r][2] + s_mu[r][3])
                                 * (1.f / 256.f);
                const float var = (s_sq[r][0] + s_sq[r][1] + s_sq[r][2] + s_sq[r][3])
                                  * (1.f / 256.f) - mu * mu;
                const float rs = rsqrtf(var + 1e-5f);
                const int m = m0 + r;
                #pragma unroll
                for (int in = 0; in < 4; ++in) {
                    const int n = cq * 64 + in * 16 + fr;
                    C[((size_t)m << 8) + n] = __float2bfloat16(
                        (acc[im][in][reg] - mu) * rs * g[n] + bln[n]);
                }
            }
        }
    } else if (tv) {
        // transposed V write: Vt[(b*4 + h)*64 + d][key], h = cq, d = in*16+fr
        const int bh = ((m0 >> 9) << 2) + cq;
        const int nn = (m0 & (N_ - 1)) + rh * 32;
        unsigned short* Ct = (unsigned short*)C;
        #pragma unroll
        for (int in = 0; in < 4; ++in) {
            const int d = in * 16 + fr;
            #pragma unroll
            for (int im = 0; im < 2; ++im) {
                unsigned short pk[4];
                #pragma unroll
                for (int reg = 0; reg < 4; ++reg) pk[reg] = f2us(acc[im][in][reg]);
                *(ushort4*)&Ct[((size_t)(bh * 64 + d) << 9) + nn + im * 16 + quad * 4]
                    = *(ushort4*)pk;
            }
        }
    } else {
        #pragma unroll
        for (int im = 0; im < 2; ++im) {
            #pragma unroll
            for (int reg = 0; reg < 4; ++reg) {
                const int m = m0 + rh * 32 + im * 16 + quad * 4 + reg;
                #pragma unroll
                for (int in = 0; in < 4; ++in) {
                    const int n = cq * 64 + in * 16 + fr;
                    C[((size_t)m << 8) + n] = __float2bfloat16(acc[im][in][reg]);
                }
            }
        }
        if (pp) {
            // mean-pool partials: column sums over this wave's 32 rows
            #pragma unroll
            for (int in = 0; in < 4; ++in) {
                float s = 0.f;
                #pragma unroll
                for (int im = 0; im < 2; ++im)
                    #pragma unroll
                    for (int reg = 0; reg < 4; ++reg) s += acc[im][in][reg];
                s += __shfl_xor(s, 16, 64);
                s += __shfl_xor(s, 32, 64);
                if (quad == 0)
                    pp[(size_t)(blockIdx.x * 2 + rh) * 256 + cq * 64 + in * 16 + fr] = s;
            }
        }
    }
}

// ---------------------------------------------------------------------------
// MFMA flash-style cross-attention (unchanged from R6).
// ---------------------------------------------------------------------------
__global__ __launch_bounds__(256)
void attn_k(const bf16* q, const bf16* __restrict__ k,
            const bf16* __restrict__ vt, bf16* ctx)
{
    __shared__ bf16 Ks[8 * 64 * 8];
    __shared__ bf16 Vs[8 * 64 * 8];
    __shared__ bf16 Ps[4 * 16 * 72];

    const int bid = blockIdx.x;
    const int l = (bid & 7) * 256 + (bid >> 3);   // XCD swizzle (2048 % 8 == 0)
    const int qt = l & 7;
    const int h  = (l >> 3) & 3;
    const int b  = l >> 5;
    const int q0 = qt * 64;
    const size_t base  = ((size_t)b * N_) * D_ + h * HD_;    // q/k/ctx
    const size_t vbase = ((size_t)(b * H_ + h) * HD_) * N_;  // Vt rows=d, cols=key

    const int tid = threadIdx.x;
    const int lane = tid & 63;
    const int w = tid >> 6;
    const int fr = lane & 15, quad = lane >> 4;

    short8 aq[2];
    #pragma unroll
    for (int ks = 0; ks < 2; ++ks)
        aq[ks] = *(const short8*)((const unsigned short*)q + base
                   + (size_t)(q0 + w * 16 + fr) * D_ + (ks * 4 + quad) * 8);

    floatx4 O[4] = {};
    float mrun[4], lrun[4];
    #pragma unroll
    for (int r = 0; r < 4; ++r) { mrun[r] = -1e30f; lrun[r] = 0.f; }

    const int srow = tid >> 2, sc = tid & 3;
    const unsigned short* kp = (const unsigned short*)k + base + (size_t)srow * D_ + sc * 16;
    const unsigned short* vp = (const unsigned short*)vt + vbase + (size_t)srow * N_ + sc * 16;
    const float C1 = 0.125f * 1.44269504f;  // scale * log2(e)

    for (int kt = 0; kt < 8; ++kt) {
        __syncthreads();
        {
            const unsigned short* srck = kp + (size_t)(kt * 64) * D_;
            *(short8*)&Ks[((sc * 2 + 0) * 64 + srow) * 8] = *(const short8*)(srck);
            *(short8*)&Ks[((sc * 2 + 1) * 64 + srow) * 8] = *(const short8*)(srck + 8);
            const unsigned short* srcv = vp + kt * 64;
            *(short8*)&Vs[((sc * 2 + 0) * 64 + srow) * 8] = *(const short8*)(srcv);
            *(short8*)&Vs[((sc * 2 + 1) * 64 + srow) * 8] = *(const short8*)(srcv + 8);
        }
        __syncthreads();

        floatx4 S[4] = {};
        __builtin_amdgcn_s_setprio(1);
        #pragma unroll
        for (int in = 0; in < 4; ++in) {
            #pragma unroll
            for (int ks = 0; ks < 2; ++ks) {
                short8 bk = *(const short8*)&Ks[((ks * 4 + quad) * 64 + in * 16 + fr) * 8];
                S[in] = __builtin_amdgcn_mfma_f32_16x16x32_bf16(aq[ks], bk, S[in], 0, 0, 0);
            }
        }
        __builtin_amdgcn_s_setprio(0);

        #pragma unroll
        for (int r = 0; r < 4; ++r) {
            float mloc = fmaxf(fmaxf(S[0][r], S[1][r]), fmaxf(S[2][r], S[3][r]));
            #pragma unroll
            for (int off = 1; off < 16; off <<= 1) mloc = fmaxf(mloc, __shfl_xor(mloc, off, 64));
            float mnew = fmaxf(mrun[r], mloc);
            float mc = mnew * C1;
            float alpha = exp2f(mrun[r] * C1 - mc);
            float rs = 0.f;
            #pragma unroll
            for (int in = 0; in < 4; ++in) {
                float p = exp2f(S[in][r] * C1 - mc);
                S[in][r] = p;
                rs += p;
            }
            #pragma unroll
            for (int off = 1; off < 16; off <<= 1) rs += __shfl_xor(rs, off, 64);
            lrun[r] = lrun[r] * alpha + rs;
            mrun[r] = mnew;
            #pragma unroll
            for (int in = 0; in < 4; ++in) O[in][r] *= alpha;
        }

        #pragma unroll
        for (int in = 0; in < 4; ++in)
            #pragma unroll
            for (int r = 0; r < 4; ++r)
                Ps[(w * 16 + quad * 4 + r) * 72 + in * 16 + fr] = __float2bfloat16(S[in][r]);
        short8 pa[2];
        #pragma unroll
        for (int ks = 0; ks < 2; ++ks)
            pa[ks] = *(const short8*)&Ps[(w * 16 + fr) * 72 + ks * 32 + quad * 8];

        __builtin_amdgcn_s_setprio(1);
        #pragma unroll
        for (int in = 0; in < 4; ++in) {
            #pragma unroll
            for (int ks = 0; ks < 2; ++ks) {
                short8 bv = *(const short8*)&Vs[((ks * 4 + quad) * 64 + in * 16 + fr) * 8];
                O[in] = __builtin_amdgcn_mfma_f32_16x16x32_bf16(pa[ks], bv, O[in], 0, 0, 0);
            }
        }
        __builtin_amdgcn_s_setprio(0);
    }

    #pragma unroll
    for (int r = 0; r < 4; ++r) {
        const float inv = 1.f / lrun[r];
        const int row = q0 + w * 16 + quad * 4 + r;
        #pragma unroll
        for (int in = 0; in < 4; ++in)
            ctx[base + (size_t)row * D_ + in * 16 + fr] = __float2bfloat16(O[in][r] * inv);
    }
}

// ---------------------------------------------------------------------------
// Mean-pool stage 2 + logits. grid B, block 256. out fp32 (B,2).
// partial: 16 chunks of 32 rows per batch.
// ---------------------------------------------------------------------------
__global__ __launch_bounds__(256)
void logits_k(const float* __restrict__ partial, const float* __restrict__ Wc,
              const float* __restrict__ bc, float* __restrict__ out)
{
    __shared__ float pl[256];
    __shared__ float red[256];
    int b = blockIdx.x, c = threadIdx.x;
    float s = 0.f;
    for (int ch = 0; ch < 16; ++ch) s += partial[((size_t)b * 16 + ch) * D_ + c];
    pl[c] = s * (1.f / 512.f);
    __syncthreads();
    int o = c >> 7, cc = c & 127;
    red[c] = pl[cc] * Wc[o * 256 + cc] + pl[cc + 128] * Wc[o * 256 + cc + 128];
    __syncthreads();
    for (int st = 64; st > 0; st >>= 1) { if (cc < st) red[c] += red[c + st]; __syncthreads(); }
    if (cc == 0) out[b * 2 + o] = red[c] + bc[o];
}

// ---------------------------------------------------------------------------
extern "C" void kernel_launch(void* const* d_in, const int* in_sizes, int n_in,
                              void* d_out, int out_size, void* d_ws, size_t ws_size,
                              hipStream_t stream)
{
    const float* x   = (const float*)d_in[0];
    const float* y   = (const float*)d_in[1];
    // d_in[2] = z, unused by the reference
    const float* Wr  = (const float*)d_in[3];
    const float* br  = (const float*)d_in[4];
    const float* Wf  = (const float*)d_in[5];
    const float* bfv = (const float*)d_in[6];
    const float* gx  = (const float*)d_in[7];
    const float* bx  = (const float*)d_in[8];
    const float* gy  = (const float*)d_in[9];
    const float* by  = (const float*)d_in[10];
    const float* Wq  = (const float*)d_in[11];
    const float* bq  = (const float*)d_in[12];
    const float* Wk  = (const float*)d_in[13];
    const float* bk  = (const float*)d_in[14];
    const float* Wv  = (const float*)d_in[15];
    const float* bv  = (const float*)d_in[16];
    const float* Wo  = (const float*)d_in[17];
    const float* bo  = (const float*)d_in[18];
    const float* gm  = (const float*)d_in[19];
    const float* bm  = (const float*)d_in[20];
    const float* W1  = (const float*)d_in[21];
    const float* b1  = (const float*)d_in[22];
    const float* W2  = (const float*)d_in[23];
    const float* b2  = (const float*)d_in[24];
    const float* Wc  = (const float*)d_in[25];
    const float* bc  = (const float*)d_in[26];

    bf16* ws = (bf16*)d_ws;
    const size_t S = (size_t)B_ * N_ * D_;          // 8,388,608 elems
    bf16*  wb   = ws;                                // weights: 778,240 elems
    float* pe   = (float*)(ws + 778240);             // 131,072 floats
    float* part = pe + 131072;                       // 262,144 floats (1024x256)
    bf16*  bA   = ws + 778240 + 6 * 131072;          // xp
    bf16*  bB   = bA + S;                            // yp -> final x_mlp
    bf16*  bC   = bB + S;                            // q  -> ctx (in-place)
    bf16*  bD   = bC + S;                            // k  -> x_res
    bf16*  bE   = bD + S;                            // Vt -> mlp hidden

    bf16* Wrb = wb;                                  // 256 x 800
    bf16* Wfb = wb + 256 * 800;                      // 256 x 704
    bf16* Wqb = Wfb + 256 * 704;
    bf16* Wkb = Wqb + 65536;
    bf16* Wvb = Wkb + 65536;
    bf16* Wob = Wvb + 65536;
    bf16* W1b = Wob + 65536;
    bf16* W2b = W1b + 65536;

    const int M = B_ * N_; // 32768 rows
    dim3 blk(256);
    dim3 blk512(512);
    dim3 grp(M / 64);                                // 512 row-panel blocks

    // constants: PE table + weight conversion
    pe_k<<<N_, blk, 0, stream>>>(pe);
    convw_k<<<dim3(100, 8), blk, 0, stream>>>(Wr, Wf, Wq, Wk, Wv, Wo, W1, W2, wb);

    // xp = LN(x @ Wr.T + br + pe)   [fp32 A direct, LN fused]
    gemm_df<true><<<grp, blk512, 0, stream>>>(nullptr, x, 0, 769, Wrb, 800,
        br, nullptr, pe, gx, bx, bA, nullptr, 800, 0, 0);
    // yp = LN(y @ Wf.T + bf + pe)
    gemm_df<true><<<grp, blk512, 0, stream>>>(nullptr, y, 0, 674, Wfb, 704,
        bfv, nullptr, pe, gy, by, bB, nullptr, 704, 0, 0);
    // q, k, v (v written transposed per (b,h): Vt[d][key])
    gemm_df<false><<<grp, blk512, 0, stream>>>(bA, nullptr, 256, 256, Wqb, 256,
        bq, nullptr, nullptr, nullptr, nullptr, bC, nullptr, 256, 0, 0);
    gemm_df<false><<<grp, blk512, 0, stream>>>(bB, nullptr, 256, 256, Wkb, 256,
        bk, nullptr, nullptr, nullptr, nullptr, bD, nullptr, 256, 0, 0);
    gemm_df<false><<<grp, blk512, 0, stream>>>(bB, nullptr, 256, 256, Wvb, 256,
        bv, nullptr, nullptr, nullptr, nullptr, bE, nullptr, 256, 0, 1);
    // attention -> ctx (in-place over q)
    attn_k<<<B_ * H_ * 8, blk, 0, stream>>>(bC, bD, bE, bC);
    // x_res = LN(xp + ctx @ Wo.T + bo)   [residual + LN fused]
    gemm_df<false><<<grp, blk512, 0, stream>>>(bC, nullptr, 256, 256, Wob, 256,
        bo, bA, nullptr, gm, bm, bD, nullptr, 256, 0, 0);
    // mlp
    gemm_df<false><<<grp, blk512, 0, stream>>>(bD, nullptr, 256, 256, W1b, 256,
        b1, nullptr, nullptr, nullptr, nullptr, bE, nullptr, 256, 1, 0);
    gemm_df<false><<<grp, blk512, 0, stream>>>(bE, nullptr, 256, 256, W2b, 256,
        b2, bD, nullptr, nullptr, nullptr, bB, part, 256, 0, 0);
    // logits
    logits_k<<<B_, blk, 0, stream>>>(part, Wc, bc, (float*)d_out);
}

// Round 8
// 527.409 us; speedup vs baseline: 1.2217x; 1.2217x over previous
//
#include <hip/hip_runtime.h>
#include <hip/hip_bf16.h>

// Problem constants
#define B_   64
#define N_   512
#define D_   256
#define H_   4
#define HD_  64

typedef __hip_bfloat16 bf16;
typedef __attribute__((ext_vector_type(8))) short short8;
typedef __attribute__((ext_vector_type(4))) float floatx4;

__device__ __forceinline__ float bf2f(bf16 v) { return __bfloat162float(v); }
__device__ __forceinline__ unsigned short f2us(float f) {
    bf16 h = __float2bfloat16(f);
    union { bf16 h; unsigned short u; } c; c.h = h; return c.u;
}

// async 16B global -> LDS DMA (gfx950). LDS dest must be wave-uniform base +
// lane*16 -- our per-lane pointers are lane-contiguous by construction.
typedef __attribute__((address_space(1))) const unsigned int asg_u32;
typedef __attribute__((address_space(3))) unsigned int asl_u32;
__device__ __forceinline__ void gl_lds16(const void* g, void* l) {
    __builtin_amdgcn_global_load_lds((asg_u32*)g, (asl_u32*)l, 16, 0, 0);
}

// counted waits (T4): keep next tile's loads in flight ACROSS the barrier.
__device__ __forceinline__ void wait_vm12() { asm volatile("s_waitcnt vmcnt(12)" ::: "memory"); }
__device__ __forceinline__ void wait_vm5()  { asm volatile("s_waitcnt vmcnt(5)"  ::: "memory"); }
__device__ __forceinline__ void wait_vm0()  { asm volatile("s_waitcnt vmcnt(0)"  ::: "memory"); }
__device__ __forceinline__ void wait_lg0()  { asm volatile("s_waitcnt lgkmcnt(0)" ::: "memory"); }
__device__ __forceinline__ void bar()       { __builtin_amdgcn_s_barrier(); }
__device__ __forceinline__ void schedb()    { __builtin_amdgcn_sched_barrier(0); }

// ---------------------------------------------------------------------------
// Weight pre-convert: fp32 -> bf16, zero-padded rows Kreal -> Kp (K%32==0).
// dst layout: Wr[256*800] Wf[256*704] Wq Wk Wv Wo W1 W2 [256*256 each].
// ---------------------------------------------------------------------------
__global__ __launch_bounds__(256)
void convw_k(const float* __restrict__ Wr, const float* __restrict__ Wf,
             const float* __restrict__ Wq, const float* __restrict__ Wk,
             const float* __restrict__ Wv, const float* __restrict__ Wo,
             const float* __restrict__ W1, const float* __restrict__ W2,
             bf16* __restrict__ dst)
{
    const int seg = blockIdx.y;
    const float* src; int Kreal, Kp; size_t off;
    switch (seg) {
        case 0: src = Wr; Kreal = 769; Kp = 800; off = 0; break;
        case 1: src = Wf; Kreal = 674; Kp = 704; off = 256 * 800; break;
        default:
            src = (seg == 2) ? Wq : (seg == 3) ? Wk : (seg == 4) ? Wv
                : (seg == 5) ? Wo : (seg == 6) ? W1 : W2;
            Kreal = 256; Kp = 256;
            off = 256 * 800 + 256 * 704 + (size_t)(seg - 2) * 256 * 256;
            break;
    }
    const int idx = blockIdx.x * 256 + threadIdx.x;   // unit = 8 outputs
    if (idx >= 256 * Kp / 8) return;
    const int rowk = idx * 8;
    const int n = rowk / Kp, k0 = rowk % Kp;
    unsigned short tmp[8];
    #pragma unroll
    for (int j = 0; j < 8; ++j) {
        int kk = k0 + j;
        tmp[j] = f2us(kk < Kreal ? src[(size_t)n * Kreal + kk] : 0.f);
    }
    *(short8*)&dst[off + (size_t)rowk] = *(short8*)tmp;
}

// ---------------------------------------------------------------------------
// Positional-embedding table: pe[n][c], n<512, c<256. grid 512 x 256 thr.
// ---------------------------------------------------------------------------
__global__ __launch_bounds__(256)
void pe_k(float* __restrict__ pe)
{
    const int n = blockIdx.x, c = threadIdx.x;
    const int j = c & ~1;
    float freq = __expf(-(float)j * (9.210340371976184f / 256.0f)); // ln(10000)/d
    float ang = (float)n * freq;
    pe[n * 256 + c] = (c & 1) ? cosf(ang) : sinf(ang);
}

// ---------------------------------------------------------------------------
// MFMA GEMM (R6 structure, measured best): 64x256 tile, BK=32, 3-buffer LDS,
// counted-vmcnt schedule. Epilogue fuses bias/PE/ReLU/residual/LN or V^T.
// ---------------------------------------------------------------------------
template<bool F32A>
__global__ __launch_bounds__(256)
void gemm_rp_t(const bf16* __restrict__ A, const float* __restrict__ A32,
               int lda, int Kreal,
               const bf16* __restrict__ W, int ldw,
               const float* __restrict__ bias, const bf16* __restrict__ res,
               const float* __restrict__ pe,
               const float* __restrict__ g, const float* __restrict__ bln,
               bf16* __restrict__ C, float* __restrict__ pp,
               int Kp, int relu, int tv)
{
    __shared__ bf16 As[3][4 * 64 * 8];     // 12 KB
    __shared__ bf16 Bs[3][4 * 256 * 8];    // 48 KB
    __shared__ float s_mu[64][4], s_sq[64][4]; // 2 KB

    const int tid = threadIdx.x;
    const int m0 = blockIdx.x * 64;
    const int lane = tid & 63, w = tid >> 6;
    const int fr = lane & 15, quad = lane >> 4;
    const int nt = Kp / 32;

    const unsigned short* Wp = (const unsigned short*)W + (size_t)lane * ldw + w * 8;

    floatx4 acc[4][4] = {};
    int rb = 0, w1 = 1, w2 = 2;            // rotating buffer indices

    if constexpr (F32A) {
        // staging map: row = tid>>2 (64 rows), k-slot = (tid&3)*8
        const int srow = tid >> 2, skb = tid & 3, kb8 = skb * 8;
        const float* a32p = A32 + (size_t)(m0 + srow) * Kreal + kb8;
        float avA[8], avB[8];

        #pragma unroll
        for (int j = 0; j < 8; ++j) avA[j] = a32p[j];           // 8 vm
        #pragma unroll
        for (int i = 0; i < 4; ++i)                              // 4 vm
            gl_lds16(Wp + (size_t)(i * 64) * ldw, &Bs[0][(w * 256 + i * 64 + lane) * 8]);
        {
            unsigned short uw[8];
            #pragma unroll
            for (int j = 0; j < 8; ++j) uw[j] = f2us(avA[j]);    // waits avA
            *(short8*)&As[0][(skb * 64 + srow) * 8] = *(short8*)uw;
        }
        #pragma unroll
        for (int j = 0; j < 8; ++j) avB[j] = a32p[32 + j];       // 8 vm
        #pragma unroll
        for (int i = 0; i < 4; ++i)                              // 4 vm
            gl_lds16(Wp + (size_t)(i * 64) * ldw + 32, &Bs[1][(w * 256 + i * 64 + lane) * 8]);

        auto f32a_step = [&](int t_, float (&AVC)[8], float (&AVN)[8]) {
            if (t_ + 1 < nt) { wait_vm12(); } else { wait_vm0(); }
            wait_lg0();
            bar();
            schedb();
            if (t_ + 2 < nt) {
                const int kL = (t_ + 2) * 32;
                if (kL + 32 <= Kreal) {
                    #pragma unroll
                    for (int j = 0; j < 8; ++j) AVN[j] = a32p[kL + j];
                } else {
                    #pragma unroll
                    for (int j = 0; j < 8; ++j) {
                        int kk = kL + kb8 + j;
                        int offv = (kk < Kreal) ? (kL + j) : 0;
                        float tvv = a32p[offv];
                        AVN[j] = (kk < Kreal) ? tvv : 0.f;
                    }
                }
                #pragma unroll
                for (int i = 0; i < 4; ++i)
                    gl_lds16(Wp + (size_t)(i * 64) * ldw + kL,
                             &Bs[w2][(w * 256 + i * 64 + lane) * 8]);
            }
            if (t_ + 1 < nt) {
                unsigned short uw[8];
                #pragma unroll
                for (int j = 0; j < 8; ++j) uw[j] = f2us(AVC[j]);
                *(short8*)&As[w1][(skb * 64 + srow) * 8] = *(short8*)uw;
            }
            schedb();
            short8 a[4];
            #pragma unroll
            for (int im = 0; im < 4; ++im)
                a[im] = *(const short8*)&As[rb][(quad * 64 + im * 16 + fr) * 8];
            #pragma unroll
            for (int in = 0; in < 4; ++in) {
                short8 bfrag = *(const short8*)&Bs[rb][(quad * 256 + w * 64 + in * 16 + fr) * 8];
                #pragma unroll
                for (int im = 0; im < 4; ++im)
                    acc[im][in] = __builtin_amdgcn_mfma_f32_16x16x32_bf16(
                        a[im], bfrag, acc[im][in], 0, 0, 0);
            }
            int tmp_ = rb; rb = w1; w1 = w2; w2 = tmp_;
        };
        for (int t = 0; t < nt; t += 2) {
            f32a_step(t, avB, avA);
            if (t + 1 < nt) f32a_step(t + 1, avA, avB);
        }
    } else {
        // A stage: wave w DMAs k-group w (1 op) + 4 B ops = 5/wave/batch.
        const unsigned short* Ap = (const unsigned short*)A + (size_t)(m0 + lane) * lda + w * 8;

        gl_lds16(Ap, &As[0][(w * 64 + lane) * 8]);
        #pragma unroll
        for (int i = 0; i < 4; ++i)
            gl_lds16(Wp + (size_t)(i * 64) * ldw, &Bs[0][(w * 256 + i * 64 + lane) * 8]);
        gl_lds16(Ap + 32, &As[1][(w * 64 + lane) * 8]);
        #pragma unroll
        for (int i = 0; i < 4; ++i)
            gl_lds16(Wp + (size_t)(i * 64) * ldw + 32, &Bs[1][(w * 256 + i * 64 + lane) * 8]);

        for (int t = 0; t < nt; ++t) {
            if (t + 1 < nt) { wait_vm5(); } else { wait_vm0(); }
            bar();
            schedb();
            if (t + 2 < nt) {
                const int kB = (t + 2) * 32;
                gl_lds16(Ap + kB, &As[w2][(w * 64 + lane) * 8]);
                #pragma unroll
                for (int i = 0; i < 4; ++i)
                    gl_lds16(Wp + (size_t)(i * 64) * ldw + kB,
                             &Bs[w2][(w * 256 + i * 64 + lane) * 8]);
            }
            schedb();
            short8 a[4];
            #pragma unroll
            for (int im = 0; im < 4; ++im)
                a[im] = *(const short8*)&As[rb][(quad * 64 + im * 16 + fr) * 8];
            #pragma unroll
            for (int in = 0; in < 4; ++in) {
                short8 bfrag = *(const short8*)&Bs[rb][(quad * 256 + w * 64 + in * 16 + fr) * 8];
                #pragma unroll
                for (int im = 0; im < 4; ++im)
                    acc[im][in] = __builtin_amdgcn_mfma_f32_16x16x32_bf16(
                        a[im], bfrag, acc[im][in], 0, 0, 0);
            }
            int tmp_ = rb; rb = w1; w1 = w2; w2 = tmp_;
        }
    }

    // ---- epilogue: bias (+pe) (+relu) (+res) ----
    #pragma unroll
    for (int in = 0; in < 4; ++in) {
        const int n = w * 64 + in * 16 + fr;
        const float bi = bias[n];
        #pragma unroll
        for (int im = 0; im < 4; ++im) {
            #pragma unroll
            for (int reg = 0; reg < 4; ++reg) {
                const int m = m0 + im * 16 + quad * 4 + reg;
                float v = acc[im][in][reg] + bi;
                if (pe)   v += pe[((m & (N_ - 1)) << 8) + n];
                if (relu) v = fmaxf(v, 0.f);
                if (res)  v += bf2f(res[((size_t)m << 8) + n]);
                acc[im][in][reg] = v;
            }
        }
    }

    if (g) {
        #pragma unroll
        for (int im = 0; im < 4; ++im) {
            #pragma unroll
            for (int reg = 0; reg < 4; ++reg) {
                float ps = acc[im][0][reg] + acc[im][1][reg]
                         + acc[im][2][reg] + acc[im][3][reg];
                float pq = acc[im][0][reg] * acc[im][0][reg]
                         + acc[im][1][reg] * acc[im][1][reg]
                         + acc[im][2][reg] * acc[im][2][reg]
                         + acc[im][3][reg] * acc[im][3][reg];
                #pragma unroll
                for (int off = 1; off < 16; off <<= 1) {
                    ps += __shfl_xor(ps, off, 64);
                    pq += __shfl_xor(pq, off, 64);
                }
                if (fr == 0) {
                    const int r = im * 16 + quad * 4 + reg;
                    s_mu[r][w] = ps;
                    s_sq[r][w] = pq;
                }
            }
        }
        __syncthreads();
        #pragma unroll
        for (int im = 0; im < 4; ++im) {
            #pragma unroll
            for (int reg = 0; reg < 4; ++reg) {
                const int r = im * 16 + quad * 4 + reg;
                const float mu = (s_mu[r][0] + s_mu[r][1] + s_mu[r][2] + s_mu[r][3])
                                 * (1.f / 256.f);
                const float var = (s_sq[r][0] + s_sq[r][1] + s_sq[r][2] + s_sq[r][3])
                                  * (1.f / 256.f) - mu * mu;
                const float rs = rsqrtf(var + 1e-5f);
                const int m = m0 + r;
                #pragma unroll
                for (int in = 0; in < 4; ++in) {
                    const int n = w * 64 + in * 16 + fr;
                    C[((size_t)m << 8) + n] = __float2bfloat16(
                        (acc[im][in][reg] - mu) * rs * g[n] + bln[n]);
                }
            }
        }
    } else {
        #pragma unroll
        for (int im = 0; im < 4; ++im) {
            #pragma unroll
            for (int reg = 0; reg < 4; ++reg) {
                const int m = m0 + im * 16 + quad * 4 + reg;
                #pragma unroll
                for (int in = 0; in < 4; ++in) {
                    const int n = w * 64 + in * 16 + fr;
                    C[((size_t)m << 8) + n] = __float2bfloat16(acc[im][in][reg]);
                }
            }
        }
    }
}

// ---------------------------------------------------------------------------
// Fused K+V projection: one pass over yp produces K (rows) and Vt (b,h-major
// transposed). 512 threads: waves 0-3 -> K cols cq*64, waves 4-7 -> V.
// Direct-fragment (no LDS, no barriers); A re-read x2 hits L2.
// ---------------------------------------------------------------------------
__global__ __launch_bounds__(512, 4)
void kv_k(const bf16* __restrict__ A,
          const bf16* __restrict__ Wk, const bf16* __restrict__ Wv,
          const float* __restrict__ bk, const float* __restrict__ bv,
          bf16* __restrict__ K, bf16* __restrict__ Vt)
{
    const int tid = threadIdx.x;
    const int m0 = blockIdx.x * 64;
    const int lane = tid & 63, w = tid >> 6;
    const int isv = w >> 2;          // 0: K-waves, 1: V-waves
    const int cq = w & 3;            // col quarter (= head for V)
    const int fr = lane & 15, quad = lane >> 4;

    const unsigned short* wp = (const unsigned short*)(isv ? Wv : Wk)
        + (size_t)(cq * 64 + fr) * 256 + quad * 8;
    const unsigned short* ap = (const unsigned short*)A
        + (size_t)(m0 + fr) * 256 + quad * 8;

    floatx4 acc[4][4] = {};
    for (int t = 0; t < 8; ++t) {
        const int k0 = t * 32;
        short8 fa[4], fb[4];
        #pragma unroll
        for (int i = 0; i < 4; ++i) {
            fa[i] = *(const short8*)(ap + (size_t)(i * 16) * 256 + k0);
            fb[i] = *(const short8*)(wp + (size_t)(i * 16) * 256 + k0);
        }
        #pragma unroll
        for (int in = 0; in < 4; ++in)
            #pragma unroll
            for (int im = 0; im < 4; ++im)
                acc[im][in] = __builtin_amdgcn_mfma_f32_16x16x32_bf16(
                    fa[im], fb[in], acc[im][in], 0, 0, 0);
    }

    const float* bias = isv ? bv : bk;
    if (!isv) {
        #pragma unroll
        for (int im = 0; im < 4; ++im) {
            #pragma unroll
            for (int reg = 0; reg < 4; ++reg) {
                const int m = m0 + im * 16 + quad * 4 + reg;
                #pragma unroll
                for (int in = 0; in < 4; ++in) {
                    const int n = cq * 64 + in * 16 + fr;
                    K[((size_t)m << 8) + n] = __float2bfloat16(acc[im][in][reg] + bias[n]);
                }
            }
        }
    } else {
        // transposed V: Vt[(b*4 + h)*64 + d][key], h = cq, d = in*16+fr
        const int bh = ((m0 >> 9) << 2) + cq;
        const int nn = m0 & (N_ - 1);
        unsigned short* Ct = (unsigned short*)Vt;
        #pragma unroll
        for (int in = 0; in < 4; ++in) {
            const int d = in * 16 + fr;
            const float bi = bias[cq * 64 + d];
            #pragma unroll
            for (int im = 0; im < 4; ++im) {
                unsigned short pk[4];
                #pragma unroll
                for (int reg = 0; reg < 4; ++reg) pk[reg] = f2us(acc[im][in][reg] + bi);
                *(ushort4*)&Ct[((size_t)(bh * 64 + d) << 9) + nn + im * 16 + quad * 4]
                    = *(ushort4*)pk;
            }
        }
    }
}

// ---------------------------------------------------------------------------
// Fused MLP: out = x_res + relu(x_res@W1^T + b1)@W2^T + b2, + pool partials.
// GEMM1 direct-fragment -> hidden in XOR-swizzled LDS (32 KB) -> GEMM2 with
// W2 rows as the MFMA A-operand and hidden rows (LDS) as B. One barrier.
// Saves the 32 MB hidden round-trip + one pass + one launch.
// ---------------------------------------------------------------------------
__global__ __launch_bounds__(256)
void mlp_k(const bf16* __restrict__ A,
           const bf16* __restrict__ W1, const float* __restrict__ b1,
           const bf16* __restrict__ W2, const float* __restrict__ b2,
           bf16* __restrict__ C, float* __restrict__ pp)
{
    __shared__ bf16 Hs[64 * 256];   // 32 KB, rows XOR-swizzled by (row&7)<<3 elems

    const int tid = threadIdx.x;
    const int m0 = blockIdx.x * 64;
    const int lane = tid & 63, cq = tid >> 6;
    const int fr = lane & 15, quad = lane >> 4;

    const unsigned short* ap  = (const unsigned short*)A  + (size_t)(m0 + fr) * 256 + quad * 8;
    const unsigned short* w1p = (const unsigned short*)W1 + (size_t)(cq * 64 + fr) * 256 + quad * 8;

    {
        floatx4 acc[4][4] = {};
        for (int t = 0; t < 8; ++t) {
            const int k0 = t * 32;
            short8 fa[4], fb[4];
            #pragma unroll
            for (int i = 0; i < 4; ++i) {
                fa[i] = *(const short8*)(ap + (size_t)(i * 16) * 256 + k0);
                fb[i] = *(const short8*)(w1p + (size_t)(i * 16) * 256 + k0);
            }
            #pragma unroll
            for (int in = 0; in < 4; ++in)
                #pragma unroll
                for (int im = 0; im < 4; ++im)
                    acc[im][in] = __builtin_amdgcn_mfma_f32_16x16x32_bf16(
                        fa[im], fb[in], acc[im][in], 0, 0, 0);
        }
        // epilogue1: +b1, relu, scatter into swizzled Hs
        #pragma unroll
        for (int in = 0; in < 4; ++in) {
            const int col = cq * 64 + in * 16 + fr;
            const float bi = b1[col];
            #pragma unroll
            for (int im = 0; im < 4; ++im) {
                #pragma unroll
                for (int reg = 0; reg < 4; ++reg) {
                    const int row = im * 16 + quad * 4 + reg;
                    const int idx = row * 256 + col;
                    Hs[idx ^ ((row & 7) << 3)] =
                        __float2bfloat16(fmaxf(acc[im][in][reg] + bi, 0.f));
                }
            }
        }
    }
    __syncthreads();

    // GEMM2: mfma(A = W2-row frags [out-cols], B = hidden-row frags [rows]).
    // C layout: fr -> hidden row m, quad*4+reg -> out col n2.
    floatx4 acc2[4][4] = {};
    const unsigned short* w2p = (const unsigned short*)W2 + (size_t)(cq * 64 + fr) * 256 + quad * 8;
    for (int t = 0; t < 8; ++t) {
        const int k0 = t * 32;
        short8 fa[4], fb[4];
        #pragma unroll
        for (int i = 0; i < 4; ++i) {
            fa[i] = *(const short8*)(w2p + (size_t)(i * 16) * 256 + k0);
            const int hrow = i * 16 + fr;
            const int idx = hrow * 256 + k0 + quad * 8;
            fb[i] = *(const short8*)&Hs[idx ^ ((hrow & 7) << 3)];
        }
        #pragma unroll
        for (int in = 0; in < 4; ++in)
            #pragma unroll
            for (int im = 0; im < 4; ++im)
                acc2[im][in] = __builtin_amdgcn_mfma_f32_16x16x32_bf16(
                    fa[im], fb[in], acc2[im][in], 0, 0, 0);
    }

    // epilogue2: +b2 +res, write C, accumulate column sums for mean-pool
    float ps[4][4];
    #pragma unroll
    for (int im = 0; im < 4; ++im)
        #pragma unroll
        for (int reg = 0; reg < 4; ++reg) ps[im][reg] = 0.f;

    #pragma unroll
    for (int im = 0; im < 4; ++im) {
        #pragma unroll
        for (int in = 0; in < 4; ++in) {
            const int m = m0 + in * 16 + fr;
            const int n2b = cq * 64 + im * 16 + quad * 4;
            const ushort4 rv = *(const ushort4*)((const unsigned short*)A
                                                 + ((size_t)m << 8) + n2b);
            const unsigned short ru[4] = { rv.x, rv.y, rv.z, rv.w };
            unsigned short pk[4];
            #pragma unroll
            for (int reg = 0; reg < 4; ++reg) {
                bf16 rb_;
                union { unsigned short u; bf16 h; } cvu; cvu.u = ru[reg]; rb_ = cvu.h;
                float v = acc2[im][in][reg] + b2[n2b + reg] + bf2f(rb_);
                ps[im][reg] += v;
                pk[reg] = f2us(v);
            }
            *(ushort4*)((unsigned short*)C + ((size_t)m << 8) + n2b) = *(ushort4*)pk;
        }
    }
    // reduce column sums over the 16 fr lanes (64 rows total incl. in-loop)
    #pragma unroll
    for (int im = 0; im < 4; ++im) {
        #pragma unroll
        for (int reg = 0; reg < 4; ++reg) {
            float s = ps[im][reg];
            s += __shfl_xor(s, 1, 64);
            s += __shfl_xor(s, 2, 64);
            s += __shfl_xor(s, 4, 64);
            s += __shfl_xor(s, 8, 64);
            if (fr == 0)
                pp[(size_t)blockIdx.x * 256 + cq * 64 + im * 16 + quad * 4 + reg] = s;
        }
    }
}

// ---------------------------------------------------------------------------
// MFMA flash-style cross-attention (unchanged from R6).
// ---------------------------------------------------------------------------
__global__ __launch_bounds__(256)
void attn_k(const bf16* q, const bf16* __restrict__ k,
            const bf16* __restrict__ vt, bf16* ctx)
{
    __shared__ bf16 Ks[8 * 64 * 8];
    __shared__ bf16 Vs[8 * 64 * 8];
    __shared__ bf16 Ps[4 * 16 * 72];

    const int bid = blockIdx.x;
    const int l = (bid & 7) * 256 + (bid >> 3);   // XCD swizzle (2048 % 8 == 0)
    const int qt = l & 7;
    const int h  = (l >> 3) & 3;
    const int b  = l >> 5;
    const int q0 = qt * 64;
    const size_t base  = ((size_t)b * N_) * D_ + h * HD_;    // q/k/ctx
    const size_t vbase = ((size_t)(b * H_ + h) * HD_) * N_;  // Vt rows=d, cols=key

    const int tid = threadIdx.x;
    const int lane = tid & 63;
    const int w = tid >> 6;
    const int fr = lane & 15, quad = lane >> 4;

    short8 aq[2];
    #pragma unroll
    for (int ks = 0; ks < 2; ++ks)
        aq[ks] = *(const short8*)((const unsigned short*)q + base
                   + (size_t)(q0 + w * 16 + fr) * D_ + (ks * 4 + quad) * 8);

    floatx4 O[4] = {};
    float mrun[4], lrun[4];
    #pragma unroll
    for (int r = 0; r < 4; ++r) { mrun[r] = -1e30f; lrun[r] = 0.f; }

    const int srow = tid >> 2, sc = tid & 3;
    const unsigned short* kp = (const unsigned short*)k + base + (size_t)srow * D_ + sc * 16;
    const unsigned short* vp = (const unsigned short*)vt + vbase + (size_t)srow * N_ + sc * 16;
    const float C1 = 0.125f * 1.44269504f;  // scale * log2(e)

    for (int kt = 0; kt < 8; ++kt) {
        __syncthreads();
        {
            const unsigned short* srck = kp + (size_t)(kt * 64) * D_;
            *(short8*)&Ks[((sc * 2 + 0) * 64 + srow) * 8] = *(const short8*)(srck);
            *(short8*)&Ks[((sc * 2 + 1) * 64 + srow) * 8] = *(const short8*)(srck + 8);
            const unsigned short* srcv = vp + kt * 64;
            *(short8*)&Vs[((sc * 2 + 0) * 64 + srow) * 8] = *(const short8*)(srcv);
            *(short8*)&Vs[((sc * 2 + 1) * 64 + srow) * 8] = *(const short8*)(srcv + 8);
        }
        __syncthreads();

        floatx4 S[4] = {};
        __builtin_amdgcn_s_setprio(1);
        #pragma unroll
        for (int in = 0; in < 4; ++in) {
            #pragma unroll
            for (int ks = 0; ks < 2; ++ks) {
                short8 bk = *(const short8*)&Ks[((ks * 4 + quad) * 64 + in * 16 + fr) * 8];
                S[in] = __builtin_amdgcn_mfma_f32_16x16x32_bf16(aq[ks], bk, S[in], 0, 0, 0);
            }
        }
        __builtin_amdgcn_s_setprio(0);

        #pragma unroll
        for (int r = 0; r < 4; ++r) {
            float mloc = fmaxf(fmaxf(S[0][r], S[1][r]), fmaxf(S[2][r], S[3][r]));
            #pragma unroll
            for (int off = 1; off < 16; off <<= 1) mloc = fmaxf(mloc, __shfl_xor(mloc, off, 64));
            float mnew = fmaxf(mrun[r], mloc);
            float mc = mnew * C1;
            float alpha = exp2f(mrun[r] * C1 - mc);
            float rs = 0.f;
            #pragma unroll
            for (int in = 0; in < 4; ++in) {
                float p = exp2f(S[in][r] * C1 - mc);
                S[in][r] = p;
                rs += p;
            }
            #pragma unroll
            for (int off = 1; off < 16; off <<= 1) rs += __shfl_xor(rs, off, 64);
            lrun[r] = lrun[r] * alpha + rs;
            mrun[r] = mnew;
            #pragma unroll
            for (int in = 0; in < 4; ++in) O[in][r] *= alpha;
        }

        #pragma unroll
        for (int in = 0; in < 4; ++in)
            #pragma unroll
            for (int r = 0; r < 4; ++r)
                Ps[(w * 16 + quad * 4 + r) * 72 + in * 16 + fr] = __float2bfloat16(S[in][r]);
        short8 pa[2];
        #pragma unroll
        for (int ks = 0; ks < 2; ++ks)
            pa[ks] = *(const short8*)&Ps[(w * 16 + fr) * 72 + ks * 32 + quad * 8];

        __builtin_amdgcn_s_setprio(1);
        #pragma unroll
        for (int in = 0; in < 4; ++in) {
            #pragma unroll
            for (int ks = 0; ks < 2; ++ks) {
                short8 bv = *(const short8*)&Vs[((ks * 4 + quad) * 64 + in * 16 + fr) * 8];
                O[in] = __builtin_amdgcn_mfma_f32_16x16x32_bf16(pa[ks], bv, O[in], 0, 0, 0);
            }
        }
        __builtin_amdgcn_s_setprio(0);
    }

    #pragma unroll
    for (int r = 0; r < 4; ++r) {
        const float inv = 1.f / lrun[r];
        const int row = q0 + w * 16 + quad * 4 + r;
        #pragma unroll
        for (int in = 0; in < 4; ++in)
            ctx[base + (size_t)row * D_ + in * 16 + fr] = __float2bfloat16(O[in][r] * inv);
    }
}

// ---------------------------------------------------------------------------
// Mean-pool stage 2 + logits. grid B, block 256. out fp32 (B,2).
// partial: 8 chunks of 64 rows per batch (from mlp_k).
// ---------------------------------------------------------------------------
__global__ __launch_bounds__(256)
void logits_k(const float* __restrict__ partial, const float* __restrict__ Wc,
              const float* __restrict__ bc, float* __restrict__ out)
{
    __shared__ float pl[256];
    __shared__ float red[256];
    int b = blockIdx.x, c = threadIdx.x;
    float s = 0.f;
    for (int ch = 0; ch < 8; ++ch) s += partial[((size_t)b * 8 + ch) * D_ + c];
    pl[c] = s * (1.f / 512.f);
    __syncthreads();
    int o = c >> 7, cc = c & 127;
    red[c] = pl[cc] * Wc[o * 256 + cc] + pl[cc + 128] * Wc[o * 256 + cc + 128];
    __syncthreads();
    for (int st = 64; st > 0; st >>= 1) { if (cc < st) red[c] += red[c + st]; __syncthreads(); }
    if (cc == 0) out[b * 2 + o] = red[c] + bc[o];
}

// ---------------------------------------------------------------------------
extern "C" void kernel_launch(void* const* d_in, const int* in_sizes, int n_in,
                              void* d_out, int out_size, void* d_ws, size_t ws_size,
                              hipStream_t stream)
{
    const float* x   = (const float*)d_in[0];
    const float* y   = (const float*)d_in[1];
    // d_in[2] = z, unused by the reference
    const float* Wr  = (const float*)d_in[3];
    const float* br  = (const float*)d_in[4];
    const float* Wf  = (const float*)d_in[5];
    const float* bfv = (const float*)d_in[6];
    const float* gx  = (const float*)d_in[7];
    const float* bx  = (const float*)d_in[8];
    const float* gy  = (const float*)d_in[9];
    const float* by  = (const float*)d_in[10];
    const float* Wq  = (const float*)d_in[11];
    const float* bq  = (const float*)d_in[12];
    const float* Wk  = (const float*)d_in[13];
    const float* bk  = (const float*)d_in[14];
    const float* Wv  = (const float*)d_in[15];
    const float* bv  = (const float*)d_in[16];
    const float* Wo  = (const float*)d_in[17];
    const float* bo  = (const float*)d_in[18];
    const float* gm  = (const float*)d_in[19];
    const float* bm  = (const float*)d_in[20];
    const float* W1  = (const float*)d_in[21];
    const float* b1  = (const float*)d_in[22];
    const float* W2  = (const float*)d_in[23];
    const float* b2  = (const float*)d_in[24];
    const float* Wc  = (const float*)d_in[25];
    const float* bc  = (const float*)d_in[26];

    bf16* ws = (bf16*)d_ws;
    const size_t S = (size_t)B_ * N_ * D_;          // 8,388,608 elems
    bf16*  wb   = ws;                                // weights: 778,240 elems
    float* pe   = (float*)(ws + 778240);             // 131,072 floats
    float* part = pe + 131072;                       // 131,072 floats
    bf16*  bA   = ws + 778240 + 4 * 131072;          // xp
    bf16*  bB   = bA + S;                            // yp -> final x_mlp
    bf16*  bC   = bB + S;                            // q  -> ctx (in-place)
    bf16*  bD   = bC + S;                            // k  -> x_res
    bf16*  bE   = bD + S;                            // Vt

    bf16* Wrb = wb;                                  // 256 x 800
    bf16* Wfb = wb + 256 * 800;                      // 256 x 704
    bf16* Wqb = Wfb + 256 * 704;
    bf16* Wkb = Wqb + 65536;
    bf16* Wvb = Wkb + 65536;
    bf16* Wob = Wvb + 65536;
    bf16* W1b = Wob + 65536;
    bf16* W2b = W1b + 65536;

    const int M = B_ * N_; // 32768 rows
    dim3 blk(256);
    dim3 blk512(512);
    dim3 grp(M / 64);                                // 512 row-panel blocks

    // constants: PE table + weight conversion
    pe_k<<<N_, blk, 0, stream>>>(pe);
    convw_k<<<dim3(100, 8), blk, 0, stream>>>(Wr, Wf, Wq, Wk, Wv, Wo, W1, W2, wb);

    // xp = LN(x @ Wr.T + br + pe)   [fp32 A staged in-kernel, LN fused]
    gemm_rp_t<true><<<grp, blk, 0, stream>>>(nullptr, x, 0, 769, Wrb, 800,
        br, nullptr, pe, gx, bx, bA, nullptr, 800, 0, 0);
    // yp = LN(y @ Wf.T + bf + pe)
    gemm_rp_t<true><<<grp, blk, 0, stream>>>(nullptr, y, 0, 674, Wfb, 704,
        bfv, nullptr, pe, gy, by, bB, nullptr, 704, 0, 0);
    // q
    gemm_rp_t<false><<<grp, blk, 0, stream>>>(bA, nullptr, 256, 256, Wqb, 256,
        bq, nullptr, nullptr, nullptr, nullptr, bC, nullptr, 256, 0, 0);
    // k + v fused (v written transposed per (b,h): Vt[d][key])
    kv_k<<<grp, blk512, 0, stream>>>(bB, Wkb, Wvb, bk, bv, bD, bE);
    // attention -> ctx (in-place over q)
    attn_k<<<B_ * H_ * 8, blk, 0, stream>>>(bC, bD, bE, bC);
    // x_res = LN(xp + ctx @ Wo.T + bo)   [residual + LN fused]
    gemm_rp_t<false><<<grp, blk, 0, stream>>>(bC, nullptr, 256, 256, Wob, 256,
        bo, bA, nullptr, gm, bm, bD, nullptr, 256, 0, 0);
    // fused MLP (W1 + relu + W2 + residual + pool partials)
    mlp_k<<<grp, blk, 0, stream>>>(bD, W1b, b1, W2b, b2, bB, part);
    // logits
    logits_k<<<B_, blk, 0, stream>>>(part, Wc, bc, (float*)d_out);
}